// Round 3
// baseline (982.633 us; speedup 1.0000x reference)
//
#include <hip/hip_runtime.h>
#include <math.h>

#define BATCH 32
#define NN 1024
#define MM 1024
#define RR 16                   // rows per lane
#define CC 8                    // cols per superstep
#define LANES 64
#define TPB (MM / CC)           // 128 supersteps per lane
#define TOT (TPB + LANES - 1)   // 191 iterations, no pipeline LAG at all
#define DEC_WORDS_PER_BATCH ((NN / 4) * (MM / 4))     // 65536 words = 256 KB
#define DEC_BYTES ((size_t)BATCH * DEC_WORDS_PER_BATCH * 4)   // 8 MB
#define REQ_WS DEC_BYTES
#define LPATH (NN + MM - 1)     // 2047

__global__ void init_kernel(float* out) { out[0] = 0.0f; }

// ---- Backtrack word-walk on 4x4 decision blocks, packed-layout addressing --
// Word for 4x4 block (ri, jc) lives at sdec[((jc>>1)<<8) + ((ri-riOff)<<1) + (jc&1)]
// (linear copy of one 32768-word half of the per-batch decision buffer).
// Bit layout within a word is the proven ((i&3)*4 + (j&3))*2 format.
__device__ inline void bt_walkP(const unsigned* __restrict__ sdec, int riOff,
                                int iLow, int& i, int& j, int& n,
                                unsigned* __restrict__ path)
{
    int ri = i >> 2, jc = j >> 2;
#define WADDR(R, C) (((((C) >> 1)) << 8) + (((R) - riOff) << 1) + ((C) & 1))
    unsigned w = sdec[WADDR(ri, jc)];
    while (true) {
        const int riu = (ri > riOff) ? ri - 1 : ri;
        const int jcl = (jc > 0) ? jc - 1 : jc;
        const unsigned wl = sdec[WADDR(ri, jcl)];
        const unsigned wu = sdec[WADDR(riu, jc)];
        const unsigned wd = sdec[WADDR(riu, jcl)];
        bool done = false, susp = false;
        while (true) {
            path[n++] = ((unsigned)i << 16) | (unsigned)j;
            if ((i | j) == 0) { done = true; break; }
            const unsigned m = (w >> (((i & 3) * 4 + (j & 3)) * 2)) & 3u;
            i -= (m != 2u); j -= (m != 1u);
            if (i < iLow) { susp = true; break; }
            if ((i >> 2) != ri || (j >> 2) != jc) break;
        }
        if (done || susp) break;
        const int nri = i >> 2, njc = j >> 2;
        w = (nri == ri) ? wl : ((njc == jc) ? wu : wd);
        ri = nri; jc = njc;
    }
#undef WADDR
}

// ---- Fused DP + backtrack: 32 blocks (one per batch) x 64 threads -----------
// SINGLE WAVE per batch. Lane l owns rows 16l..16l+15; superstep q covers
// cols 8q..8q+7; lane l runs q = u - l (pure lane skew). TOT = 191 iterations
// (vs 535 in the 4-wave pipeline) with ZERO barriers, ZERO LDS ring, ZERO
// cross-wave lag. Boundary row flows lane-to-lane via 8 __shfl_up per
// iteration; the diagonal seed is the previous superstep's bv[7] (bndRet).
// Per-cell FP ops and tie order are identical to the reference:
//   mn = min3(dg, up, lf); m = (mn==dg)?0:((mn==up)?1:2); D = cost + mn;
// (equality-form m is provably equal to the 3-compare argmin form, NaN-free).
//
// Decision words: proven 4x4-block format. Lane-tile (16x8) = 8 words,
// word k = (r>>2)*2 + (c>>2), bit ((r&3)*4 + (c&3))*2. Global layout
// (word units): b*65536 + (l>>5)*32768 + q*256 + (l&31)*8 + k  — each
// 32768-word half is a LINEAR image of sdec for the backtrack copy.
__global__ __launch_bounds__(64, 1) void dtw_fused(
    const float* __restrict__ preds, const float* __restrict__ targs,
    const float* __restrict__ subcoef, unsigned* __restrict__ dec,
    float* __restrict__ out)
{
    const int b = blockIdx.x, l = threadIdx.x;      // 64 threads = 1 wave
    const float INF = __builtin_inff();

    __shared__ float pxA[NN], pyA[NN], txA[MM], tyA[MM];   // 16 KB
    __shared__ unsigned sdec[32768];                       // 128 KB
    __shared__ unsigned path[LPATH + 1];                   // 8 KB
    __shared__ int sI, sJ, sN;

    for (int it = 0; it < NN / 64; ++it) {
        const int idx = it * 64 + l;
        const float4 p4 = ((const float4*)preds)[(size_t)b * NN + idx];
        pxA[idx] = p4.x; pyA[idx] = p4.y;
        const float4 t4 = ((const float4*)targs)[(size_t)b * MM + idx];
        txA[idx] = t4.x; tyA[idx] = t4.y;
    }
    __syncthreads();

    // ---------------- DP ----------------
    float px[RR], py[RR];
    #pragma unroll
    for (int k = 0; k < 4; ++k) {
        const float4 p4 = ((const float4*)pxA)[4 * l + k];
        px[4 * k] = p4.x; px[4 * k + 1] = p4.y; px[4 * k + 2] = p4.z; px[4 * k + 3] = p4.w;
        const float4 q4 = ((const float4*)pyA)[4 * l + k];
        py[4 * k] = q4.x; py[4 * k + 1] = q4.y; py[4 * k + 2] = q4.z; py[4 * k + 3] = q4.w;
    }
    unsigned* __restrict__ decW = dec + (size_t)b * DEC_WORDS_PER_BATCH
                                + ((size_t)(l >> 5) << 15) + ((size_t)(l & 31) << 3);

    float Dp[RR], bv[CC], bot[CC];
    #pragma unroll
    for (int r = 0; r < RR; ++r) Dp[r] = INF;
    #pragma unroll
    for (int c = 0; c < CC; ++c) { bv[c] = INF; bot[c] = INF; }
    // Diagonal seed: dg=0 at global (0,0) reproduces the reference's inf->0
    // substitution exactly (argmin=0 as well).
    float bndRet = (l == 0) ? 0.0f : INF;
    float4 tx0 = ((const float4*)txA)[0], tx1 = ((const float4*)txA)[1];
    float4 ty0 = ((const float4*)tyA)[0], ty1 = ((const float4*)tyA)[1];

    #pragma unroll 1
    for (int u = 0; u < TOT; ++u) {
        const int q = u - l;                 // this lane's superstep
        const bool act = (q >= 0) && (q < TPB);
        if (act) {
            const float cx[CC] = {tx0.x, tx0.y, tx0.z, tx0.w,
                                  tx1.x, tx1.y, tx1.z, tx1.w};
            const float cy[CC] = {ty0.x, ty0.y, ty0.z, ty0.w,
                                  ty1.x, ty1.y, ty1.z, ty1.w};
            unsigned wd[8] = {0, 0, 0, 0, 0, 0, 0, 0};
            #pragma unroll
            for (int c = 0; c < CC; ++c) {
                float up = bv[c];                        // D[16l-1][8q+c]
                float dg = (c == 0) ? bndRet : bv[c - 1];
                #pragma unroll
                for (int r = 0; r < RR; ++r) {
                    const float dx = px[r] - cx[c], dy = py[r] - cy[c];
                    const float cost = __builtin_amdgcn_sqrtf(dx * dx + dy * dy);
                    const float lf = Dp[r];              // D[16l+r][8q+c-1]
                    const float mn = fminf(dg, fminf(up, lf));   // -> v_min3
                    // Equality-form argmin, first-minimum tie order [dg,up,lf].
                    const unsigned m = (mn == dg) ? 0u : ((mn == up) ? 1u : 2u);
                    wd[(r >> 2) * 2 + (c >> 2)] |= m << (((r & 3) * 4 + (c & 3)) * 2);
                    const float D = cost + mn;
                    dg = lf; up = D; Dp[r] = D;
                }
                bot[c] = up;
            }
            uint4* dst = (uint4*)(decW + ((size_t)q << 8));
            dst[0] = make_uint4(wd[0], wd[1], wd[2], wd[3]);
            dst[1] = make_uint4(wd[4], wd[5], wd[6], wd[7]);
        }
        // Epilogue: retain diagonal, pass bottom row down one lane, prefetch.
        bndRet = bv[CC - 1];
        #pragma unroll
        for (int c = 0; c < CC; ++c) {
            bv[c] = __shfl_up(bot[c], 1);
            if (l == 0) bv[c] = INF;         // row above row 0
        }
        const int qn = u + 1 - l;
        if (qn >= 0 && qn < TPB) {
            tx0 = ((const float4*)txA)[2 * qn];
            tx1 = ((const float4*)txA)[2 * qn + 1];
            ty0 = ((const float4*)tyA)[2 * qn];
            ty1 = ((const float4*)tyA)[2 * qn + 1];
        }
    }

    __threadfence_block();   // drain dec stores (vmcnt) before re-reading
    __syncthreads();

    // ---------------- Backtrack ----------------
    const unsigned* __restrict__ decB = dec + (size_t)b * DEC_WORDS_PER_BATCH;
    // Phase A: lanes 32..63 (rows 512..1023) — linear 128 KB copy.
    {
        const uint4* g4 = (const uint4*)(decB + 32768);
        uint4* s4 = (uint4*)sdec;
        for (int k = l; k < 8192; k += 64) s4[k] = g4[k];
    }
    __syncthreads();
    if (l == 0) {
        int i = NN - 1, j = MM - 1, n = 0;
        bt_walkP(sdec, 128, 512, i, j, n, path);
        sI = i; sJ = j; sN = n;
    }
    __syncthreads();
    // Phase B: lanes 0..31 (rows 0..511).
    {
        const uint4* g4 = (const uint4*)decB;
        uint4* s4 = (uint4*)sdec;
        for (int k = l; k < 8192; k += 64) s4[k] = g4[k];
    }
    __syncthreads();
    if (l == 0) {
        int i = sI, j = sJ, n = sN;
        bt_walkP(sdec, 0, 0, i, j, n, path);
        sN = n;
    }
    __syncthreads();

    // ---------------- Parallel loss over the path ----------------
    const float sc0 = subcoef[0], sc1 = subcoef[1];
    const int n = sN;
    float acc = 0.0f;
    for (int p = l; p < n; p += 64) {
        const unsigned e = path[p];
        const int i = (int)(e >> 16), j = (int)(e & 0xffffu);
        acc += fabsf(pxA[i] - txA[j]) * sc0 + fabsf(pyA[i] - tyA[j]) * sc1;
    }
    #pragma unroll
    for (int o = 32; o > 0; o >>= 1) acc += __shfl_down(acc, o);
    if (l == 0) atomicAdd(out, acc);
}

// ------------- Fallback (R1 kernel, only if ws too small) --------------------
__global__ __launch_bounds__(256) void dtw_fallback(
    const float* __restrict__ preds, const float* __restrict__ targs,
    const float* __restrict__ subcoef, unsigned* __restrict__ dec,
    float* __restrict__ out)
{
    const int b = blockIdx.x;
    const int t = threadIdx.x;
    const float INF = __builtin_inff();
    __shared__ float px[NN], py[NN];
    __shared__ float txy[2 * MM];
    __shared__ float bbuf[2][256];

    for (int it = 0; it < NN / 256; ++it) {
        const int idx = it * 256 + t;
        const float4 p4 = ((const float4*)preds)[(size_t)b * NN + idx];
        px[idx] = p4.x; py[idx] = p4.y;
        const float4 t4 = ((const float4*)targs)[(size_t)b * MM + idx];
        txy[2 * idx] = t4.x; txy[2 * idx + 1] = t4.y;
    }
    bbuf[0][t] = INF; bbuf[1][t] = INF;
    __syncthreads();

    float pxr[4], pyr[4], Dp[4];
    #pragma unroll
    for (int r = 0; r < 4; ++r) {
        pxr[r] = px[4 * t + r]; pyr[r] = py[4 * t + r]; Dp[r] = INF;
    }
    float dgB = (t == 0) ? 0.0f : INF;
    unsigned packed = 0;
    unsigned* decB = dec + (size_t)b * 65536;
    for (int s = 0; s < MM + 255; ++s) {
        const int j = s - t;
        const float upB = (t == 0) ? INF : bbuf[(s + 1) & 1][t - 1];
        if (j >= 0 && j < MM) {
            const float txj = txy[2 * j], tyj = txy[2 * j + 1];
            float up = upB, dg = dgB;
            unsigned mbits = 0;
            #pragma unroll
            for (int r = 0; r < 4; ++r) {
                const float dx = pxr[r] - txj, dy = pyr[r] - tyj;
                const float c = sqrtf(dx * dx + dy * dy);
                const float lf = Dp[r];
                const unsigned m = (dg <= up && dg <= lf) ? 0u
                                 : ((up <= lf) ? 1u : 2u);
                mbits |= m << (r * 8 + (j & 3) * 2);
                const float Dc = c + fminf(up, fminf(dg, lf));
                dg = lf; up = Dc; Dp[r] = Dc;
            }
            packed |= mbits;
            if ((j & 3) == 3) { decB[(unsigned)t * 256 + (j >> 2)] = packed; packed = 0; }
            bbuf[s & 1][t] = Dp[3];
        }
        dgB = upB;
        __syncthreads();
    }
    __threadfence_block();
    __syncthreads();
    if (t == 0) {
        const float sc0 = subcoef[0], sc1 = subcoef[1];
        int i = NN - 1, jj = MM - 1;
        float loss = 0.0f;
        int ti = i >> 2, tj = jj >> 2;
        unsigned wv = decB[ti * 256 + tj];
        while (true) {
            const int tjl = (tj > 0) ? tj - 1 : 0;
            const int til = (ti > 0) ? ti - 1 : 0;
            const unsigned wl = decB[ti * 256 + tjl];
            const unsigned wu = decB[til * 256 + tj];
            const unsigned wd = decB[til * 256 + tjl];
            bool done = false;
            while (true) {
                loss += fabsf(px[i] - txy[2 * jj]) * sc0
                      + fabsf(py[i] - txy[2 * jj + 1]) * sc1;
                if ((i | jj) == 0) { done = true; break; }
                const unsigned m = (wv >> (((i & 3) * 4 + (jj & 3)) * 2)) & 3u;
                i -= (m != 2u); jj -= (m != 1u);
                if ((i >> 2) != ti || (jj >> 2) != tj) break;
            }
            if (done) break;
            const int nti = i >> 2, ntj = jj >> 2;
            wv = (nti == ti) ? wl : ((ntj == tj) ? wu : wd);
            ti = nti; tj = ntj;
        }
        atomicAdd(out, loss);
    }
}

extern "C" void kernel_launch(void* const* d_in, const int* in_sizes, int n_in,
                              void* d_out, int out_size, void* d_ws, size_t ws_size,
                              hipStream_t stream) {
    const float* preds   = (const float*)d_in[0];
    const float* targs   = (const float*)d_in[1];
    const float* subcoef = (const float*)d_in[2];
    float* out = (float*)d_out;
    unsigned* dec = (unsigned*)d_ws;   // 8 MB

    init_kernel<<<1, 1, 0, stream>>>(out);
    if (ws_size >= REQ_WS) {
        dtw_fused<<<BATCH, 64, 0, stream>>>(preds, targs, subcoef, dec, out);
    } else {
        dtw_fallback<<<BATCH, 256, 0, stream>>>(preds, targs, subcoef, dec, out);
    }
}

// Round 4
// 578.476 us; speedup vs baseline: 1.6987x; 1.6987x over previous
//
#include <hip/hip_runtime.h>
#include <math.h>

#define BATCH 32
#define NN 1024
#define MM 1024
#define LPATH (NN + MM - 1)     // 2047

// ---------------- New wavefront-panel geometry ----------------
// 8x8 grid of 128x128 panels per batch. Panel = 1 wave, lane owns 2 rows.
// 15 diagonal launches; boundaries flow through ws between launches.
#define PB 128                  // panel rows
#define PQ 128                  // panel cols
#define GB 8                    // bands (rows of panels)
#define GH 8                    // panel columns
#define PAN_WORDS 1536          // 24 sblk x 64 lanes (4 bits/step/lane, 192 steps)
#define BAT_WORDS (GB * GH * PAN_WORDS)               // 98304 words / batch
#define RCPL (9 * 1024)                               // rcol/brow plane floats
#define RC_OFFW ((size_t)BATCH * BAT_WORDS)           // 3,145,728 words
#define BR_OFFW (RC_OFFW + (size_t)BATCH * RCPL)
#define WS_WORDS (BR_OFFW + (size_t)BATCH * RCPL)
#define REQ_WS_NEW (WS_WORDS * 4)                     // ~14.3 MB

// Legacy (proven 557us) path requirement
#define DEC_WORDS_PER_BATCH ((NN / 4) * (MM / 4))     // 65536
#define REQ_WS ((size_t)BATCH * DEC_WORDS_PER_BATCH * 4)   // 8 MB

__global__ void init_kernel(float* out) { out[0] = 0.0f; }

// ---- init for new path: INF boundary planes (c=0 / r=0) + out=0 ------------
__global__ void init2(float* __restrict__ ws, float* __restrict__ out)
{
    const int b = blockIdx.x, t = threadIdx.x;
    const float INF = __builtin_inff();
    if (b == 0 && t == 0) out[0] = 0.0f;
    float* rc0 = ws + RC_OFFW + (size_t)b * RCPL;     // rcol[b][0][*]
    float* br0 = ws + BR_OFFW + (size_t)b * RCPL;     // brow[b][0][*]
    for (int i = t; i < 1024; i += 256) { rc0[i] = INF; br0[i] = INF; }
}

// ---- Panel DP kernel: launch per grid anti-diagonal -------------------------
// Lane l owns panel-rows 2l, 2l+1. Step s (0..191): lane l computes panel-col
// jq = s - l for both its rows (predicated to jq in [0,128)). Boundary flows:
// up via __shfl_up of neighbor's row-1 D (lane 0: top row from brow), dg via
// previous step's up (lane 0 jq==0: corner), lf via own D registers (init =
// left column from rcol). Decisions: 4 bits/step/lane (2 cells x 2 bits),
// word = 8 steps, flushed wave-uniformly -> coalesced 256B store; layout
// dec[b][r*8+c][s>>3][lane]. Per-cell FP math identical to the proven kernel.
__global__ __launch_bounds__(64, 1) void dtw_panel(
    const float* __restrict__ preds, const float* __restrict__ targs,
    float* __restrict__ ws, const int diag)
{
    const int b = blockIdx.y;
    const int r0 = (diag > GH - 1) ? diag - (GH - 1) : 0;
    const int r = r0 + blockIdx.x;
    const int c = diag - r;
    const int l = threadIdx.x;
    const float INF = __builtin_inff();

    __shared__ __align__(16) float txP[260], tyP[260];   // padded col streams
    __shared__ __align__(16) float TL[200];              // top row stream
    __shared__ __align__(16) float botL[128];            // bottom row collect

    // pads (reads for inactive jq land here; values unused)
    if (l < 63) { txP[l] = 0.f; tyP[l] = 0.f; }
    txP[191 + l] = 0.f; tyP[191 + l] = 0.f;
    if (l < 6) { txP[255 + l] = 0.f; tyP[255 + l] = 0.f; }
    TL[128 + l] = INF; if (l < 8) TL[192 + l] = INF;

    // stage targ cols [128c .. 128c+127] (basis x,y = features 0,1)
    const float4* tg4 = (const float4*)targs + (size_t)b * MM + c * PQ;
    {
        const float4 a = tg4[l], e = tg4[64 + l];
        txP[63 + l] = a.x;      tyP[63 + l] = a.y;
        txP[63 + 64 + l] = e.x; tyP[63 + 64 + l] = e.y;
    }
    // top boundary row (brow[b][r] holds D of global row 128r-1; r=0 -> INF)
    const float* browR = ws + BR_OFFW + ((size_t)b * 9 + r) * 1024 + c * PQ;
    TL[l] = browR[l]; TL[64 + l] = browR[64 + l];

    // pred rows
    const float4* pp4 = (const float4*)preds + (size_t)b * NN + r * PB;
    const float4 p0 = pp4[2 * l], p1 = pp4[2 * l + 1];
    const float px0 = p0.x, py0 = p0.y, px1 = p1.x, py1 = p1.y;

    // left boundary (rcol[b][c] holds D of global col 128c-1; c=0 -> INF)
    const float* rc = ws + RC_OFFW + ((size_t)b * 9 + c) * 1024 + r * PB;
    float D0 = rc[2 * l], D1 = rc[2 * l + 1];
    const float corner = (c == 0) ? ((r == 0) ? 0.0f : INF) : browR[-1];
    const float dg0init = (l == 0) ? corner : rc[2 * l - 1];

    unsigned* __restrict__ decP = (unsigned*)ws + (size_t)b * BAT_WORDS
                                + (size_t)(r * GH + c) * PAN_WORDS + l;
    __syncthreads();

    // 8-slot register ring for tx/ty, prefetch distance 4 steps
    float txb[8], tyb[8];
    #pragma unroll
    for (int k = 0; k < 4; ++k) { txb[k] = txP[63 + k - l]; tyb[k] = tyP[63 + k - l]; }
    float up0prev = INF;

    for (int it = 0; it < 24; ++it) {
        const int s0 = it * 8;
        const float4 T4a = *(const float4*)&TL[s0];
        const float4 T4b = *(const float4*)&TL[s0 + 4];
        const float Tv[8] = {T4a.x, T4a.y, T4a.z, T4a.w,
                             T4b.x, T4b.y, T4b.z, T4b.w};
        unsigned word = 0;
        #pragma unroll
        for (int k = 0; k < 8; ++k) {
            const int s = s0 + k;
            const int jq = s - l;
            txb[(k + 4) & 7] = txP[63 + jq + 4];
            tyb[(k + 4) & 7] = tyP[63 + jq + 4];
            const float sh = __shfl_up(D1, 1);
            const float up0 = (l == 0) ? Tv[k] : sh;
            const float dg0 = (jq == 0) ? dg0init : up0prev;
            const float tx = txb[k], ty = tyb[k];
            // cell (row 2l): math identical to proven kernel (absmax=0)
            const float dx0 = px0 - tx, dy0 = py0 - ty;
            const float c0 = __builtin_amdgcn_sqrtf(dx0 * dx0 + dy0 * dy0);
            const float mn0 = fminf(dg0, fminf(up0, D0));
            const float D0n = c0 + mn0;
            const unsigned m0 = (mn0 == dg0) ? 0u : ((mn0 == up0) ? 1u : 2u);
            // cell (row 2l+1)
            const float dg1 = D0;
            const float dx1 = px1 - tx, dy1 = py1 - ty;
            const float c1 = __builtin_amdgcn_sqrtf(dx1 * dx1 + dy1 * dy1);
            const float mn1 = fminf(dg1, fminf(D0n, D1));
            const float D1n = c1 + mn1;
            const unsigned m1 = (mn1 == dg1) ? 0u : ((mn1 == D0n) ? 1u : 2u);
            word |= (m0 | (m1 << 2)) << (4 * k);
            const bool act = (jq >= 0) && (jq < PQ);
            if (act) { D0 = D0n; D1 = D1n; }
            up0prev = up0;
            if (l == 63 && act) botL[jq] = D1n;   // band bottom row
        }
        decP[it * 64] = word;                     // coalesced 256B store
    }

    // publish right column (D regs frozen at jq=127 by predication)
    float* rcw = ws + RC_OFFW + ((size_t)b * 9 + (c + 1)) * 1024 + r * PB;
    rcw[2 * l] = D0; rcw[2 * l + 1] = D1;
    __syncthreads();
    float* brw = ws + BR_OFFW + ((size_t)b * 9 + (r + 1)) * 1024 + c * PQ;
    brw[l] = botL[l]; brw[64 + l] = botL[64 + l];
}

// ---- Backtrack + loss: 32 blocks x 256 threads ------------------------------
// Stages decisions two bands (96KB) at a time, t0 walks with word caching,
// then the proven parallel-loss reduction.
__global__ __launch_bounds__(256, 1) void dtw_bt(
    const float* __restrict__ preds, const float* __restrict__ targs,
    const float* __restrict__ subcoef, const float* __restrict__ ws,
    float* __restrict__ out)
{
    const int b = blockIdx.x, t = threadIdx.x;
    __shared__ float pxA[NN], pyA[NN], txA[MM], tyA[MM];   // 16 KB
    __shared__ __align__(16) unsigned sdec[24576];         // 96 KB (2 bands)
    __shared__ unsigned path[2048];                        // 8 KB
    __shared__ int sI, sJ, sN;
    __shared__ float wsum[4];

    for (int it = 0; it < 4; ++it) {
        const int idx = it * 256 + t;
        const float4 p4 = ((const float4*)preds)[(size_t)b * NN + idx];
        pxA[idx] = p4.x; pyA[idx] = p4.y;
        const float4 t4 = ((const float4*)targs)[(size_t)b * MM + idx];
        txA[idx] = t4.x; tyA[idx] = t4.y;
    }
    if (t == 0) { sI = NN - 1; sJ = MM - 1; sN = 0; }

    const unsigned* decB = (const unsigned*)ws + (size_t)b * BAT_WORDS;
    for (int pair = 3; pair >= 0; --pair) {
        __syncthreads();                    // prior walk done before overwrite
        const uint4* g4 = (const uint4*)(decB + (size_t)pair * 24576);
        uint4* s4 = (uint4*)sdec;
        for (int k = t; k < 6144; k += 256) s4[k] = g4[k];
        __syncthreads();
        if (t == 0) {
            int i = sI, j = sJ, n = sN;
            const int iLow = pair * 256;
            if (i >= iLow) {
                int cwidx = -1; unsigned cw = 0;
                while (true) {
                    path[n++] = ((unsigned)i << 16) | (unsigned)j;
                    if ((i | j) == 0) { i = -1; break; }
                    const int rr = i >> 7, cc = j >> 7;
                    const int ll = (i & 127) >> 1;
                    const int ss = ll + (j & 127);
                    const int widx = ((rr - 2 * pair) * GH + cc) * PAN_WORDS
                                   + (ss >> 3) * 64 + ll;
                    if (widx != cwidx) { cw = sdec[widx]; cwidx = widx; }
                    const unsigned m = (cw >> ((ss & 7) * 4 + (i & 1) * 2)) & 3u;
                    i -= (m != 2u); j -= (m != 1u);
                    if (i < iLow) break;
                }
            }
            sI = i; sJ = j; sN = n;
        }
    }
    __syncthreads();

    // parallel loss over the path (verbatim from proven kernel)
    const float sc0 = subcoef[0], sc1 = subcoef[1];
    const int n = sN;
    float acc = 0.0f;
    for (int p = t; p < n; p += 256) {
        const unsigned e = path[p];
        const int i = (int)(e >> 16), j = (int)(e & 0xffffu);
        acc += fabsf(pxA[i] - txA[j]) * sc0 + fabsf(pyA[i] - tyA[j]) * sc1;
    }
    #pragma unroll
    for (int o = 32; o > 0; o >>= 1) acc += __shfl_down(acc, o);
    if ((t & 63) == 0) wsum[t >> 6] = acc;
    __syncthreads();
    if (t == 0) atomicAdd(out, (wsum[0] + wsum[1]) + (wsum[2] + wsum[3]));
}

// =================== Legacy proven path (557us, needs 8MB) ===================
__device__ inline void bt_walk4(const unsigned* __restrict__ sdec, int roff,
                                int iLow, int& i, int& j, int& n,
                                unsigned* __restrict__ path)
{
    int ri = i >> 2, jc = j >> 2;
    unsigned w = sdec[(ri - roff) * 256 + jc];
    while (true) {
        const int base = (ri - roff) * 256 + jc;
        const unsigned wl = sdec[(jc > 0)    ? base - 1   : base];
        const unsigned wu = sdec[(ri > roff) ? base - 256 : base];
        const unsigned wd = sdec[(ri > roff && jc > 0) ? base - 257 : base];
        bool done = false, susp = false;
        while (true) {
            path[n++] = ((unsigned)i << 16) | (unsigned)j;
            if ((i | j) == 0) { done = true; break; }
            const unsigned m = (w >> (((i & 3) * 4 + (j & 3)) * 2)) & 3u;
            i -= (m != 2u); j -= (m != 1u);
            if (i < iLow) { susp = true; break; }
            if ((i >> 2) != ri || (j >> 2) != jc) break;
        }
        if (done || susp) break;
        const int nri = i >> 2, njc = j >> 2;
        w = (nri == ri) ? wl : ((njc == jc) ? wu : wd);
        ri = nri; jc = njc;
    }
}

#define RRL 4
#define CCL 4
#define LANES 64
#define NWAVE 4
#define TPBL (MM / 4)
#define NSUP (TPBL + LANES - 1)
#define LAG 72
#define TOTL (NSUP + (NWAVE - 1) * LAG)
#define DEPTH 32

__global__ __launch_bounds__(256, 1) void dtw_fused_legacy(
    const float* __restrict__ preds, const float* __restrict__ targs,
    const float* __restrict__ subcoef, unsigned* __restrict__ dec,
    float* __restrict__ out)
{
    const int b = blockIdx.x, t = threadIdx.x;
    const int l = t & 63, w = t >> 6;
    const float INF = __builtin_inff();

    __shared__ float pxA[NN], pyA[NN], txA[MM], tyA[MM];
    __shared__ float4 ring[NWAVE - 1][DEPTH];
    __shared__ unsigned sdec[128 * 256];
    __shared__ unsigned path[LPATH + 1];
    __shared__ int sI, sJ, sN;
    __shared__ float wsum[NWAVE];

    for (int it = 0; it < NN / 256; ++it) {
        const int idx = it * 256 + t;
        const float4 p4 = ((const float4*)preds)[(size_t)b * NN + idx];
        pxA[idx] = p4.x; pyA[idx] = p4.y;
        const float4 t4 = ((const float4*)targs)[(size_t)b * MM + idx];
        txA[idx] = t4.x; tyA[idx] = t4.y;
    }
    __syncthreads();

    const int i0 = (w << 8) + (l << 2);
    const float4 px4 = ((const float4*)pxA)[i0 >> 2];
    const float4 py4 = ((const float4*)pyA)[i0 >> 2];
    const float px[RRL] = {px4.x, px4.y, px4.z, px4.w};
    const float py[RRL] = {py4.x, py4.y, py4.z, py4.w};
    unsigned* __restrict__ decW =
        dec + (size_t)b * DEC_WORDS_PER_BATCH + ((size_t)w << 14) + (size_t)l;

    float Dp[RRL], Dbot[CCL], bv[CCL];
    #pragma unroll
    for (int r = 0; r < RRL; ++r) Dp[r] = INF;
    #pragma unroll
    for (int c = 0; c < CCL; ++c) { Dbot[c] = INF; bv[c] = INF; }
    float bndRet = (w == 0 && l == 0) ? 0.0f : INF;
    float4 gcur = make_float4(INF, INF, INF, INF);
    float4 tx4 = ((const float4*)txA)[0], ty4 = ((const float4*)tyA)[0];
    const float4* __restrict__ ringR = ring[(w > 0) ? (w - 1) : 0];

    for (int u = 0; u < TOTL; ++u) {
        const int ul = u - LAG * w;
        if (l == 0) {
            const bool gb = (w > 0) && (ul >= 0) && (ul < TPBL);
            bv[0] = gb ? gcur.x : INF; bv[1] = gb ? gcur.y : INF;
            bv[2] = gb ? gcur.z : INF; bv[3] = gb ? gcur.w : INF;
        }
        const bool act = (ul >= l) && (ul < l + TPBL);
        if (act) {
            const float cx[CCL] = {tx4.x, tx4.y, tx4.z, tx4.w};
            const float cy[CCL] = {ty4.x, ty4.y, ty4.z, ty4.w};
            float cost[RRL][CCL];
            #pragma unroll
            for (int c = 0; c < CCL; ++c)
                #pragma unroll
                for (int r = 0; r < RRL; ++r) {
                    const float dx = px[r] - cx[c], dy = py[r] - cy[c];
                    cost[r][c] = __builtin_amdgcn_sqrtf(dx * dx + dy * dy);
                }
            unsigned word = 0;
            #pragma unroll
            for (int c = 0; c < CCL; ++c) {
                float up = bv[c];
                float dg = (c == 0) ? bndRet : bv[c - 1];
                #pragma unroll
                for (int r = 0; r < RRL; ++r) {
                    const float lf = Dp[r];
                    const unsigned m = (dg <= up && dg <= lf) ? 0u
                                     : ((up <= lf) ? 1u : 2u);
                    const float D = cost[r][c] + fminf(dg, fminf(up, lf));
                    word |= m << ((r * 4 + c) * 2);
                    dg = lf; up = D; Dp[r] = D;
                }
                Dbot[c] = up;
            }
            decW[(ul & 255) << 6] = word;
            if (l == LANES - 1 && w < NWAVE - 1)
                ring[w][ul & (DEPTH - 1)] =
                    make_float4(Dbot[0], Dbot[1], Dbot[2], Dbot[3]);
        }
        bndRet = bv[CCL - 1];
        #pragma unroll
        for (int c = 0; c < CCL; ++c) bv[c] = __shfl_up(Dbot[c], 1);
        const int un = ul + 1;
        if (un >= l && un < l + TPBL) {
            const int jn = CCL * (un - l);
            tx4 = ((const float4*)txA)[jn >> 2];
            ty4 = ((const float4*)tyA)[jn >> 2];
        }
        if (w > 0 && un >= 0 && un < TPBL)
            gcur = ringR[(un + 63) & (DEPTH - 1)];
        if ((u & 7) == 7) __syncthreads();
    }

    __threadfence_block();
    __syncthreads();

    const unsigned* __restrict__ decB = dec + (size_t)b * DEC_WORDS_PER_BATCH;
    {
        const uint4* g4 = (const uint4*)(decB + 32768);
        for (int k = t; k < 8192; k += 256) {
            const uint4 v = g4[k];
            const int kb = k << 2;
            const int wv = kb >> 14;
            const int rem = kb & 16383;
            const int q = rem >> 6;
            const int lb = rem & 63;
            const unsigned wd[4] = {v.x, v.y, v.z, v.w};
            #pragma unroll
            for (int e = 0; e < 4; ++e) {
                const int ll = lb + e;
                const int row = (wv << 6) + ll;
                const int jc = (q - ll) & 255;
                sdec[(row << 8) + jc] = wd[e];
            }
        }
    }
    __syncthreads();
    if (t == 0) {
        int i = NN - 1, j = MM - 1, n = 0;
        bt_walk4(sdec, 128, 512, i, j, n, path);
        sI = i; sJ = j; sN = n;
    }
    __syncthreads();
    {
        const uint4* g4 = (const uint4*)decB;
        for (int k = t; k < 8192; k += 256) {
            const uint4 v = g4[k];
            const int kb = k << 2;
            const int wv = kb >> 14;
            const int rem = kb & 16383;
            const int q = rem >> 6;
            const int lb = rem & 63;
            const unsigned wd[4] = {v.x, v.y, v.z, v.w};
            #pragma unroll
            for (int e = 0; e < 4; ++e) {
                const int ll = lb + e;
                const int row = (wv << 6) + ll;
                const int jc = (q - ll) & 255;
                sdec[(row << 8) + jc] = wd[e];
            }
        }
    }
    __syncthreads();
    if (t == 0) {
        int i = sI, j = sJ, n = sN;
        bt_walk4(sdec, 0, 0, i, j, n, path);
        sN = n;
    }
    __syncthreads();

    const float sc0 = subcoef[0], sc1 = subcoef[1];
    const int n = sN;
    float acc = 0.0f;
    for (int p = t; p < n; p += 256) {
        const unsigned e = path[p];
        const int i = (int)(e >> 16), j = (int)(e & 0xffffu);
        acc += fabsf(pxA[i] - txA[j]) * sc0 + fabsf(pyA[i] - tyA[j]) * sc1;
    }
    #pragma unroll
    for (int o = 32; o > 0; o >>= 1) acc += __shfl_down(acc, o);
    if ((t & 63) == 0) wsum[t >> 6] = acc;
    __syncthreads();
    if (t == 0) atomicAdd(out, (wsum[0] + wsum[1]) + (wsum[2] + wsum[3]));
}

// ------------- Fallback (only if ws too small for everything) ----------------
__global__ __launch_bounds__(256) void dtw_fallback(
    const float* __restrict__ preds, const float* __restrict__ targs,
    const float* __restrict__ subcoef, unsigned* __restrict__ dec,
    float* __restrict__ out)
{
    const int b = blockIdx.x;
    const int t = threadIdx.x;
    const float INF = __builtin_inff();
    __shared__ float px[NN], py[NN];
    __shared__ float txy[2 * MM];
    __shared__ float bbuf[2][256];

    for (int it = 0; it < NN / 256; ++it) {
        const int idx = it * 256 + t;
        const float4 p4 = ((const float4*)preds)[(size_t)b * NN + idx];
        px[idx] = p4.x; py[idx] = p4.y;
        const float4 t4 = ((const float4*)targs)[(size_t)b * MM + idx];
        txy[2 * idx] = t4.x; txy[2 * idx + 1] = t4.y;
    }
    bbuf[0][t] = INF; bbuf[1][t] = INF;
    __syncthreads();

    float pxr[4], pyr[4], Dp[4];
    #pragma unroll
    for (int r = 0; r < 4; ++r) {
        pxr[r] = px[4 * t + r]; pyr[r] = py[4 * t + r]; Dp[r] = INF;
    }
    float dgB = (t == 0) ? 0.0f : INF;
    unsigned packed = 0;
    unsigned* decB = dec + (size_t)b * 65536;
    for (int s = 0; s < MM + 255; ++s) {
        const int j = s - t;
        const float upB = (t == 0) ? INF : bbuf[(s + 1) & 1][t - 1];
        if (j >= 0 && j < MM) {
            const float txj = txy[2 * j], tyj = txy[2 * j + 1];
            float up = upB, dg = dgB;
            unsigned mbits = 0;
            #pragma unroll
            for (int r = 0; r < 4; ++r) {
                const float dx = pxr[r] - txj, dy = pyr[r] - tyj;
                const float c = sqrtf(dx * dx + dy * dy);
                const float lf = Dp[r];
                const unsigned m = (dg <= up && dg <= lf) ? 0u
                                 : ((up <= lf) ? 1u : 2u);
                mbits |= m << (r * 8 + (j & 3) * 2);
                const float Dc = c + fminf(up, fminf(dg, lf));
                dg = lf; up = Dc; Dp[r] = Dc;
            }
            packed |= mbits;
            if ((j & 3) == 3) { decB[(unsigned)t * 256 + (j >> 2)] = packed; packed = 0; }
            bbuf[s & 1][t] = Dp[3];
        }
        dgB = upB;
        __syncthreads();
    }
    __threadfence_block();
    __syncthreads();
    if (t == 0) {
        const float sc0 = subcoef[0], sc1 = subcoef[1];
        int i = NN - 1, jj = MM - 1;
        float loss = 0.0f;
        int ti = i >> 2, tj = jj >> 2;
        unsigned wv = decB[ti * 256 + tj];
        while (true) {
            const int tjl = (tj > 0) ? tj - 1 : 0;
            const int til = (ti > 0) ? ti - 1 : 0;
            const unsigned wl = decB[ti * 256 + tjl];
            const unsigned wu = decB[til * 256 + tj];
            const unsigned wd = decB[til * 256 + tjl];
            bool done = false;
            while (true) {
                loss += fabsf(px[i] - txy[2 * jj]) * sc0
                      + fabsf(py[i] - txy[2 * jj + 1]) * sc1;
                if ((i | jj) == 0) { done = true; break; }
                const unsigned m = (wv >> (((i & 3) * 4 + (jj & 3)) * 2)) & 3u;
                i -= (m != 2u); jj -= (m != 1u);
                if ((i >> 2) != ti || (jj >> 2) != tj) break;
            }
            if (done) break;
            const int nti = i >> 2, ntj = jj >> 2;
            wv = (nti == ti) ? wl : ((ntj == tj) ? wu : wd);
            ti = nti; tj = ntj;
        }
        atomicAdd(out, loss);
    }
}

extern "C" void kernel_launch(void* const* d_in, const int* in_sizes, int n_in,
                              void* d_out, int out_size, void* d_ws, size_t ws_size,
                              hipStream_t stream) {
    const float* preds   = (const float*)d_in[0];
    const float* targs   = (const float*)d_in[1];
    const float* subcoef = (const float*)d_in[2];
    float* out = (float*)d_out;

    if (ws_size >= REQ_WS_NEW) {
        float* wsf = (float*)d_ws;
        init2<<<BATCH, 256, 0, stream>>>(wsf, out);
        for (int d = 0; d < GB + GH - 1; ++d) {
            const int r0 = (d > GH - 1) ? d - (GH - 1) : 0;
            const int r1 = (d < GB - 1) ? d : GB - 1;
            dim3 grid(r1 - r0 + 1, BATCH);
            dtw_panel<<<grid, 64, 0, stream>>>(preds, targs, wsf, d);
        }
        dtw_bt<<<BATCH, 256, 0, stream>>>(preds, targs, subcoef, wsf, out);
    } else if (ws_size >= REQ_WS) {
        unsigned* dec = (unsigned*)d_ws;
        init_kernel<<<1, 1, 0, stream>>>(out);
        dtw_fused_legacy<<<BATCH, 256, 0, stream>>>(preds, targs, subcoef, dec, out);
    } else {
        unsigned* dec = (unsigned*)d_ws;
        init_kernel<<<1, 1, 0, stream>>>(out);
        dtw_fallback<<<BATCH, 256, 0, stream>>>(preds, targs, subcoef, dec, out);
    }
}

// Round 5
// 540.335 us; speedup vs baseline: 1.8186x; 1.0706x over previous
//
#include <hip/hip_runtime.h>
#include <math.h>

#define BATCH 32
#define NN 1024
#define MM 1024
#define LPATH (NN + MM - 1)     // 2047

// ---------------- Wavefront-panel geometry ----------------
// 8x8 grid of 128x128 panels per batch. Panel = 1 wave, lane owns 2 rows.
// 15 diagonal launches; boundaries flow through ws between launches.
#define PB 128                  // panel rows
#define PQ 128                  // panel cols
#define GB 8                    // bands (rows of panels)
#define GH 8                    // panel columns
#define PAN_WORDS 1536          // 24 sblk x 64 lanes (4 bits/step/lane, 192 steps)
#define BAT_WORDS (GB * GH * PAN_WORDS)               // 98304 words / batch
#define RCPL (9 * 1024)                               // rcol/brow plane floats
#define RC_OFFW ((size_t)BATCH * BAT_WORDS)           // 3,145,728 words
#define BR_OFFW (RC_OFFW + (size_t)BATCH * RCPL)
#define WS_WORDS (BR_OFFW + (size_t)BATCH * RCPL)
#define REQ_WS_NEW (WS_WORDS * 4)                     // ~14.3 MB

// Legacy (proven 557us) path requirement
#define DEC_WORDS_PER_BATCH ((NN / 4) * (MM / 4))     // 65536
#define REQ_WS ((size_t)BATCH * DEC_WORDS_PER_BATCH * 4)   // 8 MB

__global__ void init_kernel(float* out) { out[0] = 0.0f; }

// ---- init for new path: INF boundary planes (c=0 / r=0) + out=0 ------------
__global__ void init2(float* __restrict__ ws, float* __restrict__ out)
{
    const int b = blockIdx.x, t = threadIdx.x;
    const float INF = __builtin_inff();
    if (b == 0 && t == 0) out[0] = 0.0f;
    float* rc0 = ws + RC_OFFW + (size_t)b * RCPL;     // rcol[b][0][*]
    float* br0 = ws + BR_OFFW + (size_t)b * RCPL;     // brow[b][0][*]
    for (int i = t; i < 1024; i += 256) { rc0[i] = INF; br0[i] = INF; }
}

// ---- Panel DP kernel: launch per grid anti-diagonal -------------------------
// Lane l owns panel-rows 2l, 2l+1. Step s (0..191): lane l computes panel-col
// jq = s - l (predicated to jq in [0,128)). R5 change: the per-step cross-lane
// boundary move (D1 of lane l-1) uses DPP WF_SR1 (wavefront shift right 1,
// dpp_ctrl 0x138) -- a VALU op -- instead of __shfl_up's ds_bpermute. This
// removes the ~140-cycle LDS round-trip from the serial chain of every step.
// Lane 0 keeps its own D1 (old operand), exactly like __shfl_up(D1,1); the
// existing (l==0) select overrides it with the top boundary. Numerics are
// bit-identical to the R4-verified kernel (absmax=0).
__device__ __forceinline__ float wave_shr1(float v)
{
    return __int_as_float(__builtin_amdgcn_update_dpp(
        __float_as_int(v), __float_as_int(v), 0x138, 0xF, 0xF, false));
}

__global__ __launch_bounds__(64, 1) void dtw_panel(
    const float* __restrict__ preds, const float* __restrict__ targs,
    float* __restrict__ ws, const int diag)
{
    const int b = blockIdx.y;
    const int r0 = (diag > GH - 1) ? diag - (GH - 1) : 0;
    const int r = r0 + blockIdx.x;
    const int c = diag - r;
    const int l = threadIdx.x;
    const float INF = __builtin_inff();

    __shared__ __align__(16) float txP[260], tyP[260];   // padded col streams
    __shared__ __align__(16) float TL[200];              // top row stream
    __shared__ __align__(16) float botL[128];            // bottom row collect

    // pads (reads for inactive jq land here; values unused)
    if (l < 63) { txP[l] = 0.f; tyP[l] = 0.f; }
    txP[191 + l] = 0.f; tyP[191 + l] = 0.f;
    if (l < 6) { txP[255 + l] = 0.f; tyP[255 + l] = 0.f; }
    TL[128 + l] = INF; if (l < 8) TL[192 + l] = INF;

    // stage targ cols [128c .. 128c+127] (basis x,y = features 0,1)
    const float4* tg4 = (const float4*)targs + (size_t)b * MM + c * PQ;
    {
        const float4 a = tg4[l], e = tg4[64 + l];
        txP[63 + l] = a.x;      tyP[63 + l] = a.y;
        txP[63 + 64 + l] = e.x; tyP[63 + 64 + l] = e.y;
    }
    // top boundary row (brow[b][r] holds D of global row 128r-1; r=0 -> INF)
    const float* browR = ws + BR_OFFW + ((size_t)b * 9 + r) * 1024 + c * PQ;
    TL[l] = browR[l]; TL[64 + l] = browR[64 + l];

    // pred rows
    const float4* pp4 = (const float4*)preds + (size_t)b * NN + r * PB;
    const float4 p0 = pp4[2 * l], p1 = pp4[2 * l + 1];
    const float px0 = p0.x, py0 = p0.y, px1 = p1.x, py1 = p1.y;

    // left boundary (rcol[b][c] holds D of global col 128c-1; c=0 -> INF)
    const float* rc = ws + RC_OFFW + ((size_t)b * 9 + c) * 1024 + r * PB;
    float D0 = rc[2 * l], D1 = rc[2 * l + 1];
    const float corner = (c == 0) ? ((r == 0) ? 0.0f : INF) : browR[-1];
    const float dg0init = (l == 0) ? corner : rc[2 * l - 1];

    unsigned* __restrict__ decP = (unsigned*)ws + (size_t)b * BAT_WORDS
                                + (size_t)(r * GH + c) * PAN_WORDS + l;
    __syncthreads();

    // 8-slot register ring for tx/ty, prefetch distance 4 steps
    float txb[8], tyb[8];
    #pragma unroll
    for (int k = 0; k < 4; ++k) { txb[k] = txP[63 + k - l]; tyb[k] = tyP[63 + k - l]; }
    float up0prev = INF;

    for (int it = 0; it < 24; ++it) {
        const int s0 = it * 8;
        const float4 T4a = *(const float4*)&TL[s0];
        const float4 T4b = *(const float4*)&TL[s0 + 4];
        const float Tv[8] = {T4a.x, T4a.y, T4a.z, T4a.w,
                             T4b.x, T4b.y, T4b.z, T4b.w};
        unsigned word = 0;
        #pragma unroll
        for (int k = 0; k < 8; ++k) {
            const int s = s0 + k;
            const int jq = s - l;
            txb[(k + 4) & 7] = txP[63 + jq + 4];
            tyb[(k + 4) & 7] = tyP[63 + jq + 4];
            const float sh = wave_shr1(D1);           // lane l-1's D1, no DS
            const float up0 = (l == 0) ? Tv[k] : sh;
            const float dg0 = (jq == 0) ? dg0init : up0prev;
            const float tx = txb[k], ty = tyb[k];
            // cell (row 2l): math identical to proven kernel (absmax=0)
            const float dx0 = px0 - tx, dy0 = py0 - ty;
            const float c0 = __builtin_amdgcn_sqrtf(dx0 * dx0 + dy0 * dy0);
            const float mn0 = fminf(dg0, fminf(up0, D0));
            const float D0n = c0 + mn0;
            const unsigned m0 = (mn0 == dg0) ? 0u : ((mn0 == up0) ? 1u : 2u);
            // cell (row 2l+1)
            const float dg1 = D0;
            const float dx1 = px1 - tx, dy1 = py1 - ty;
            const float c1 = __builtin_amdgcn_sqrtf(dx1 * dx1 + dy1 * dy1);
            const float mn1 = fminf(dg1, fminf(D0n, D1));
            const float D1n = c1 + mn1;
            const unsigned m1 = (mn1 == dg1) ? 0u : ((mn1 == D0n) ? 1u : 2u);
            word |= (m0 | (m1 << 2)) << (4 * k);
            const bool act = (jq >= 0) && (jq < PQ);
            if (act) { D0 = D0n; D1 = D1n; }
            up0prev = up0;
            if (l == 63 && act) botL[jq] = D1n;   // band bottom row
        }
        decP[it * 64] = word;                     // coalesced 256B store
    }

    // publish right column (D regs frozen at jq=127 by predication)
    float* rcw = ws + RC_OFFW + ((size_t)b * 9 + (c + 1)) * 1024 + r * PB;
    rcw[2 * l] = D0; rcw[2 * l + 1] = D1;
    __syncthreads();
    float* brw = ws + BR_OFFW + ((size_t)b * 9 + (r + 1)) * 1024 + c * PQ;
    brw[l] = botL[l]; brw[64 + l] = botL[64 + l];
}

// ---- Backtrack + loss: 32 blocks x 256 threads ------------------------------
// R5 change: NO LDS staging -- t0 walks straight out of global memory (dec is
// L2-resident; word is re-fetched only when the (lane, step-block, panel)
// word index changes, ~every 3-5 moves). Removes the four serialized 96 KB
// staging rounds that dominated R4's 154 us. Walk logic otherwise identical
// to R4 (absmax=0 verified).
__global__ __launch_bounds__(256, 1) void dtw_bt(
    const float* __restrict__ preds, const float* __restrict__ targs,
    const float* __restrict__ subcoef, const float* __restrict__ ws,
    float* __restrict__ out)
{
    const int b = blockIdx.x, t = threadIdx.x;
    __shared__ float pxA[NN], pyA[NN], txA[MM], tyA[MM];   // 16 KB
    __shared__ unsigned path[2048];                        // 8 KB
    __shared__ int sN;
    __shared__ float wsum[4];

    for (int it = 0; it < 4; ++it) {
        const int idx = it * 256 + t;
        const float4 p4 = ((const float4*)preds)[(size_t)b * NN + idx];
        pxA[idx] = p4.x; pyA[idx] = p4.y;
        const float4 t4 = ((const float4*)targs)[(size_t)b * MM + idx];
        txA[idx] = t4.x; tyA[idx] = t4.y;
    }
    __syncthreads();

    if (t == 0) {
        const unsigned* __restrict__ decB =
            (const unsigned*)ws + (size_t)b * BAT_WORDS;
        int i = NN - 1, j = MM - 1, n = 0;
        int cwidx = -1; unsigned cw = 0;
        while (true) {
            path[n++] = ((unsigned)i << 16) | (unsigned)j;
            if ((i | j) == 0) break;
            const int ll = (i & 127) >> 1;
            const int ss = ll + (j & 127);
            const int widx = (((i >> 7) << 3) + (j >> 7)) * PAN_WORDS
                           + (ss >> 3) * 64 + ll;
            if (widx != cwidx) { cw = decB[widx]; cwidx = widx; }
            const unsigned m = (cw >> ((ss & 7) * 4 + (i & 1) * 2)) & 3u;
            i -= (m != 2u); j -= (m != 1u);
        }
        sN = n;
    }
    __syncthreads();

    // parallel loss over the path (verbatim from proven kernel)
    const float sc0 = subcoef[0], sc1 = subcoef[1];
    const int n = sN;
    float acc = 0.0f;
    for (int p = t; p < n; p += 256) {
        const unsigned e = path[p];
        const int i = (int)(e >> 16), j = (int)(e & 0xffffu);
        acc += fabsf(pxA[i] - txA[j]) * sc0 + fabsf(pyA[i] - tyA[j]) * sc1;
    }
    #pragma unroll
    for (int o = 32; o > 0; o >>= 1) acc += __shfl_down(acc, o);
    if ((t & 63) == 0) wsum[t >> 6] = acc;
    __syncthreads();
    if (t == 0) atomicAdd(out, (wsum[0] + wsum[1]) + (wsum[2] + wsum[3]));
}

// =================== Legacy proven path (557us, needs 8MB) ===================
__device__ inline void bt_walk4(const unsigned* __restrict__ sdec, int roff,
                                int iLow, int& i, int& j, int& n,
                                unsigned* __restrict__ path)
{
    int ri = i >> 2, jc = j >> 2;
    unsigned w = sdec[(ri - roff) * 256 + jc];
    while (true) {
        const int base = (ri - roff) * 256 + jc;
        const unsigned wl = sdec[(jc > 0)    ? base - 1   : base];
        const unsigned wu = sdec[(ri > roff) ? base - 256 : base];
        const unsigned wd = sdec[(ri > roff && jc > 0) ? base - 257 : base];
        bool done = false, susp = false;
        while (true) {
            path[n++] = ((unsigned)i << 16) | (unsigned)j;
            if ((i | j) == 0) { done = true; break; }
            const unsigned m = (w >> (((i & 3) * 4 + (j & 3)) * 2)) & 3u;
            i -= (m != 2u); j -= (m != 1u);
            if (i < iLow) { susp = true; break; }
            if ((i >> 2) != ri || (j >> 2) != jc) break;
        }
        if (done || susp) break;
        const int nri = i >> 2, njc = j >> 2;
        w = (nri == ri) ? wl : ((njc == jc) ? wu : wd);
        ri = nri; jc = njc;
    }
}

#define RRL 4
#define CCL 4
#define LANES 64
#define NWAVE 4
#define TPBL (MM / 4)
#define NSUP (TPBL + LANES - 1)
#define LAG 72
#define TOTL (NSUP + (NWAVE - 1) * LAG)
#define DEPTH 32

__global__ __launch_bounds__(256, 1) void dtw_fused_legacy(
    const float* __restrict__ preds, const float* __restrict__ targs,
    const float* __restrict__ subcoef, unsigned* __restrict__ dec,
    float* __restrict__ out)
{
    const int b = blockIdx.x, t = threadIdx.x;
    const int l = t & 63, w = t >> 6;
    const float INF = __builtin_inff();

    __shared__ float pxA[NN], pyA[NN], txA[MM], tyA[MM];
    __shared__ float4 ring[NWAVE - 1][DEPTH];
    __shared__ unsigned sdec[128 * 256];
    __shared__ unsigned path[LPATH + 1];
    __shared__ int sI, sJ, sN;
    __shared__ float wsum[NWAVE];

    for (int it = 0; it < NN / 256; ++it) {
        const int idx = it * 256 + t;
        const float4 p4 = ((const float4*)preds)[(size_t)b * NN + idx];
        pxA[idx] = p4.x; pyA[idx] = p4.y;
        const float4 t4 = ((const float4*)targs)[(size_t)b * MM + idx];
        txA[idx] = t4.x; tyA[idx] = t4.y;
    }
    __syncthreads();

    const int i0 = (w << 8) + (l << 2);
    const float4 px4 = ((const float4*)pxA)[i0 >> 2];
    const float4 py4 = ((const float4*)pyA)[i0 >> 2];
    const float px[RRL] = {px4.x, px4.y, px4.z, px4.w};
    const float py[RRL] = {py4.x, py4.y, py4.z, py4.w};
    unsigned* __restrict__ decW =
        dec + (size_t)b * DEC_WORDS_PER_BATCH + ((size_t)w << 14) + (size_t)l;

    float Dp[RRL], Dbot[CCL], bv[CCL];
    #pragma unroll
    for (int r = 0; r < RRL; ++r) Dp[r] = INF;
    #pragma unroll
    for (int c = 0; c < CCL; ++c) { Dbot[c] = INF; bv[c] = INF; }
    float bndRet = (w == 0 && l == 0) ? 0.0f : INF;
    float4 gcur = make_float4(INF, INF, INF, INF);
    float4 tx4 = ((const float4*)txA)[0], ty4 = ((const float4*)tyA)[0];
    const float4* __restrict__ ringR = ring[(w > 0) ? (w - 1) : 0];

    for (int u = 0; u < TOTL; ++u) {
        const int ul = u - LAG * w;
        if (l == 0) {
            const bool gb = (w > 0) && (ul >= 0) && (ul < TPBL);
            bv[0] = gb ? gcur.x : INF; bv[1] = gb ? gcur.y : INF;
            bv[2] = gb ? gcur.z : INF; bv[3] = gb ? gcur.w : INF;
        }
        const bool act = (ul >= l) && (ul < l + TPBL);
        if (act) {
            const float cx[CCL] = {tx4.x, tx4.y, tx4.z, tx4.w};
            const float cy[CCL] = {ty4.x, ty4.y, ty4.z, ty4.w};
            float cost[RRL][CCL];
            #pragma unroll
            for (int c = 0; c < CCL; ++c)
                #pragma unroll
                for (int r = 0; r < RRL; ++r) {
                    const float dx = px[r] - cx[c], dy = py[r] - cy[c];
                    cost[r][c] = __builtin_amdgcn_sqrtf(dx * dx + dy * dy);
                }
            unsigned word = 0;
            #pragma unroll
            for (int c = 0; c < CCL; ++c) {
                float up = bv[c];
                float dg = (c == 0) ? bndRet : bv[c - 1];
                #pragma unroll
                for (int r = 0; r < RRL; ++r) {
                    const float lf = Dp[r];
                    const unsigned m = (dg <= up && dg <= lf) ? 0u
                                     : ((up <= lf) ? 1u : 2u);
                    const float D = cost[r][c] + fminf(dg, fminf(up, lf));
                    word |= m << ((r * 4 + c) * 2);
                    dg = lf; up = D; Dp[r] = D;
                }
                Dbot[c] = up;
            }
            decW[(ul & 255) << 6] = word;
            if (l == LANES - 1 && w < NWAVE - 1)
                ring[w][ul & (DEPTH - 1)] =
                    make_float4(Dbot[0], Dbot[1], Dbot[2], Dbot[3]);
        }
        bndRet = bv[CCL - 1];
        #pragma unroll
        for (int c = 0; c < CCL; ++c) bv[c] = __shfl_up(Dbot[c], 1);
        const int un = ul + 1;
        if (un >= l && un < l + TPBL) {
            const int jn = CCL * (un - l);
            tx4 = ((const float4*)txA)[jn >> 2];
            ty4 = ((const float4*)tyA)[jn >> 2];
        }
        if (w > 0 && un >= 0 && un < TPBL)
            gcur = ringR[(un + 63) & (DEPTH - 1)];
        if ((u & 7) == 7) __syncthreads();
    }

    __threadfence_block();
    __syncthreads();

    const unsigned* __restrict__ decB = dec + (size_t)b * DEC_WORDS_PER_BATCH;
    {
        const uint4* g4 = (const uint4*)(decB + 32768);
        for (int k = t; k < 8192; k += 256) {
            const uint4 v = g4[k];
            const int kb = k << 2;
            const int wv = kb >> 14;
            const int rem = kb & 16383;
            const int q = rem >> 6;
            const int lb = rem & 63;
            const unsigned wd[4] = {v.x, v.y, v.z, v.w};
            #pragma unroll
            for (int e = 0; e < 4; ++e) {
                const int ll = lb + e;
                const int row = (wv << 6) + ll;
                const int jc = (q - ll) & 255;
                sdec[(row << 8) + jc] = wd[e];
            }
        }
    }
    __syncthreads();
    if (t == 0) {
        int i = NN - 1, j = MM - 1, n = 0;
        bt_walk4(sdec, 128, 512, i, j, n, path);
        sI = i; sJ = j; sN = n;
    }
    __syncthreads();
    {
        const uint4* g4 = (const uint4*)decB;
        for (int k = t; k < 8192; k += 256) {
            const uint4 v = g4[k];
            const int kb = k << 2;
            const int wv = kb >> 14;
            const int rem = kb & 16383;
            const int q = rem >> 6;
            const int lb = rem & 63;
            const unsigned wd[4] = {v.x, v.y, v.z, v.w};
            #pragma unroll
            for (int e = 0; e < 4; ++e) {
                const int ll = lb + e;
                const int row = (wv << 6) + ll;
                const int jc = (q - ll) & 255;
                sdec[(row << 8) + jc] = wd[e];
            }
        }
    }
    __syncthreads();
    if (t == 0) {
        int i = sI, j = sJ, n = sN;
        bt_walk4(sdec, 0, 0, i, j, n, path);
        sN = n;
    }
    __syncthreads();

    const float sc0 = subcoef[0], sc1 = subcoef[1];
    const int n = sN;
    float acc = 0.0f;
    for (int p = t; p < n; p += 256) {
        const unsigned e = path[p];
        const int i = (int)(e >> 16), j = (int)(e & 0xffffu);
        acc += fabsf(pxA[i] - txA[j]) * sc0 + fabsf(pyA[i] - tyA[j]) * sc1;
    }
    #pragma unroll
    for (int o = 32; o > 0; o >>= 1) acc += __shfl_down(acc, o);
    if ((t & 63) == 0) wsum[t >> 6] = acc;
    __syncthreads();
    if (t == 0) atomicAdd(out, (wsum[0] + wsum[1]) + (wsum[2] + wsum[3]));
}

// ------------- Fallback (only if ws too small for everything) ----------------
__global__ __launch_bounds__(256) void dtw_fallback(
    const float* __restrict__ preds, const float* __restrict__ targs,
    const float* __restrict__ subcoef, unsigned* __restrict__ dec,
    float* __restrict__ out)
{
    const int b = blockIdx.x;
    const int t = threadIdx.x;
    const float INF = __builtin_inff();
    __shared__ float px[NN], py[NN];
    __shared__ float txy[2 * MM];
    __shared__ float bbuf[2][256];

    for (int it = 0; it < NN / 256; ++it) {
        const int idx = it * 256 + t;
        const float4 p4 = ((const float4*)preds)[(size_t)b * NN + idx];
        px[idx] = p4.x; py[idx] = p4.y;
        const float4 t4 = ((const float4*)targs)[(size_t)b * MM + idx];
        txy[2 * idx] = t4.x; txy[2 * idx + 1] = t4.y;
    }
    bbuf[0][t] = INF; bbuf[1][t] = INF;
    __syncthreads();

    float pxr[4], pyr[4], Dp[4];
    #pragma unroll
    for (int r = 0; r < 4; ++r) {
        pxr[r] = px[4 * t + r]; pyr[r] = py[4 * t + r]; Dp[r] = INF;
    }
    float dgB = (t == 0) ? 0.0f : INF;
    unsigned packed = 0;
    unsigned* decB = dec + (size_t)b * 65536;
    for (int s = 0; s < MM + 255; ++s) {
        const int j = s - t;
        const float upB = (t == 0) ? INF : bbuf[(s + 1) & 1][t - 1];
        if (j >= 0 && j < MM) {
            const float txj = txy[2 * j], tyj = txy[2 * j + 1];
            float up = upB, dg = dgB;
            unsigned mbits = 0;
            #pragma unroll
            for (int r = 0; r < 4; ++r) {
                const float dx = pxr[r] - txj, dy = pyr[r] - tyj;
                const float c = sqrtf(dx * dx + dy * dy);
                const float lf = Dp[r];
                const unsigned m = (dg <= up && dg <= lf) ? 0u
                                 : ((up <= lf) ? 1u : 2u);
                mbits |= m << (r * 8 + (j & 3) * 2);
                const float Dc = c + fminf(up, fminf(dg, lf));
                dg = lf; up = Dc; Dp[r] = Dc;
            }
            packed |= mbits;
            if ((j & 3) == 3) { decB[(unsigned)t * 256 + (j >> 2)] = packed; packed = 0; }
            bbuf[s & 1][t] = Dp[3];
        }
        dgB = upB;
        __syncthreads();
    }
    __threadfence_block();
    __syncthreads();
    if (t == 0) {
        const float sc0 = subcoef[0], sc1 = subcoef[1];
        int i = NN - 1, jj = MM - 1;
        float loss = 0.0f;
        int ti = i >> 2, tj = jj >> 2;
        unsigned wv = decB[ti * 256 + tj];
        while (true) {
            const int tjl = (tj > 0) ? tj - 1 : 0;
            const int til = (ti > 0) ? ti - 1 : 0;
            const unsigned wl = decB[ti * 256 + tjl];
            const unsigned wu = decB[til * 256 + tj];
            const unsigned wd = decB[til * 256 + tjl];
            bool done = false;
            while (true) {
                loss += fabsf(px[i] - txy[2 * jj]) * sc0
                      + fabsf(py[i] - txy[2 * jj + 1]) * sc1;
                if ((i | jj) == 0) { done = true; break; }
                const unsigned m = (wv >> (((i & 3) * 4 + (jj & 3)) * 2)) & 3u;
                i -= (m != 2u); jj -= (m != 1u);
                if ((i >> 2) != ti || (jj >> 2) != tj) break;
            }
            if (done) break;
            const int nti = i >> 2, ntj = jj >> 2;
            wv = (nti == ti) ? wl : ((ntj == tj) ? wu : wd);
            ti = nti; tj = ntj;
        }
        atomicAdd(out, loss);
    }
}

extern "C" void kernel_launch(void* const* d_in, const int* in_sizes, int n_in,
                              void* d_out, int out_size, void* d_ws, size_t ws_size,
                              hipStream_t stream) {
    const float* preds   = (const float*)d_in[0];
    const float* targs   = (const float*)d_in[1];
    const float* subcoef = (const float*)d_in[2];
    float* out = (float*)d_out;

    if (ws_size >= REQ_WS_NEW) {
        float* wsf = (float*)d_ws;
        init2<<<BATCH, 256, 0, stream>>>(wsf, out);
        for (int d = 0; d < GB + GH - 1; ++d) {
            const int r0 = (d > GH - 1) ? d - (GH - 1) : 0;
            const int r1 = (d < GB - 1) ? d : GB - 1;
            dim3 grid(r1 - r0 + 1, BATCH);
            dtw_panel<<<grid, 64, 0, stream>>>(preds, targs, wsf, d);
        }
        dtw_bt<<<BATCH, 256, 0, stream>>>(preds, targs, subcoef, wsf, out);
    } else if (ws_size >= REQ_WS) {
        unsigned* dec = (unsigned*)d_ws;
        init_kernel<<<1, 1, 0, stream>>>(out);
        dtw_fused_legacy<<<BATCH, 256, 0, stream>>>(preds, targs, subcoef, dec, out);
    } else {
        unsigned* dec = (unsigned*)d_ws;
        init_kernel<<<1, 1, 0, stream>>>(out);
        dtw_fallback<<<BATCH, 256, 0, stream>>>(preds, targs, subcoef, dec, out);
    }
}